// Round 20
// baseline (181.627 us; speedup 1.0000x reference)
//
#include <hip/hip_runtime.h>

typedef __attribute__((ext_vector_type(8))) short short8;
typedef __attribute__((ext_vector_type(2))) float f32x2;
typedef __attribute__((ext_vector_type(4))) float f32x4;
typedef __attribute__((ext_vector_type(16))) float f32x16;
typedef unsigned short u16;
typedef unsigned int u32;

// 0.125 (1/sqrt(64)) * log2(e): folded into q so softmax can use exp2 directly
#define SCQ 0.18033688011112042f

__device__ __forceinline__ u16 f2b(float f) {
  unsigned u = __builtin_bit_cast(unsigned, f);
  u += 0x7FFFu + ((u >> 16) & 1u);
  return (u16)(u >> 16);
}

__device__ __forceinline__ u32 cvtpk(float a, float b) {
  u32 r;
  asm("v_cvt_pk_bf16_f32 %0, %1, %2" : "=v"(r) : "v"(a), "v"(b));
  return r;
}

// bare v_exp_f32 (scores |s| <~ 10, libm range-fixup provably dead; r10: -35us VALU)
__device__ __forceinline__ float ex2(float x) { return __builtin_amdgcn_exp2f(x); }

// async global->LDS, 16B per lane; LDS dest = wave-uniform base + lane*16
__device__ __forceinline__ void gl_lds16(const u16* g, u16* l) {
  __builtin_amdgcn_global_load_lds(
      (const __attribute__((address_space(1))) unsigned int*)g,
      (__attribute__((address_space(3))) unsigned int*)l, 16, 0, 0);
}

// ---------------- fp32 -> bf16 conversion (x, qkv_w [q-rows pre-scaled], out_w) ---
__global__ __launch_bounds__(256) void convert_k(
    const float* __restrict__ x, const float* __restrict__ w1, const float* __restrict__ w2,
    u16* __restrict__ xb, u16* __restrict__ w1b, u16* __restrict__ w2b) {
  const int NXv = (8192 * 512) / 4;
  const int NW1v = (1536 * 512) / 4;
  const int NW2v = (512 * 512) / 4;
  int i = blockIdx.x * 256 + threadIdx.x;
  const float4* src;
  u16* dst;
  int j;
  float scale = 1.0f;
  if (i < NXv) {
    src = (const float4*)x; dst = xb; j = i;
  } else if (i < NXv + NW1v) {
    j = i - NXv; src = (const float4*)w1; dst = w1b;
    if (j < (512 * 512) / 4) scale = SCQ;  // q-weight rows
  } else {
    j = i - NXv - NW1v;
    if (j >= NW2v) return;
    src = (const float4*)w2; dst = w2b;
  }
  float4 v = src[j];
  ushort4 o;
  o.x = f2b(v.x * scale); o.y = f2b(v.y * scale);
  o.z = f2b(v.z * scale); o.w = f2b(v.w * scale);
  *reinterpret_cast<ushort4*>(dst + (size_t)j * 4) = o;
}

// ---------------- QKV GEMM v4: double-buffered glds + LDS-transposed epilogue -----
__global__ __launch_bounds__(256) void qkv_gemm(
    const u16* __restrict__ Ab, const u16* __restrict__ Bw, const float* __restrict__ bias,
    u16* __restrict__ Qd, u16* __restrict__ Kd, u16* __restrict__ Vtd) {
  const int m0 = blockIdx.x * 128, n0 = blockIdx.y * 128;
  const int tid = threadIdx.x, wave = tid >> 6, lane = tid & 63;
  const int g = lane >> 4, lr = lane & 15;
  const int wm = (wave >> 1) * 64, wn = (wave & 1) * 64;
  __shared__ alignas(16) u16 smem[32768];  // 64KB: A dbuf @0/8192, B dbuf @16384/24576

  f32x4 acc[4][4];
#pragma unroll
  for (int mf = 0; mf < 4; ++mf)
#pragma unroll
    for (int nf = 0; nf < 4; ++nf)
#pragma unroll
      for (int r = 0; r < 4; ++r) acc[mf][nf][r] = 0.0f;

  const int gid0 = wave * 64 + lane;

#define QKV_STAGE(buf, k0)                                                         \
  {                                                                                \
    u16* Ad_ = smem + (buf) * 8192;                                                \
    u16* Bd_ = smem + 16384 + (buf) * 8192;                                        \
    _Pragma("unroll")                                                              \
    for (int c = 0; c < 4; ++c) {                                                  \
      const int gid = c * 256 + gid0;                                              \
      const int row = gid >> 3;                                                    \
      const int col = ((gid & 7) ^ (row & 7)) << 3;                                \
      gl_lds16(Ab + (size_t)(m0 + row) * 512 + (k0) + col,                         \
               Ad_ + (size_t)(c * 256 + wave * 64) * 8);                           \
      gl_lds16(Bw + (size_t)(n0 + row) * 512 + (k0) + col,                         \
               Bd_ + (size_t)(c * 256 + wave * 64) * 8);                           \
    }                                                                              \
  }

  QKV_STAGE(0, 0);
  __syncthreads();

#pragma unroll 1
  for (int kt = 0; kt < 8; ++kt) {
    const int cur = kt & 1;
    if (kt + 1 < 8) QKV_STAGE(cur ^ 1, (kt + 1) * 64);

    const u16* Ac = smem + cur * 8192;
    const u16* Bc = smem + 16384 + cur * 8192;
#pragma unroll
    for (int kb = 0; kb < 2; ++kb) {
      short8 bf[4], af[4];
#pragma unroll
      for (int nf = 0; nf < 4; ++nf)
        bf[nf] = *reinterpret_cast<const short8*>(
            &Bc[(wn + nf * 16 + lr) * 64 + (((kb * 4 + g) ^ (lr & 7)) << 3)]);
#pragma unroll
      for (int mf = 0; mf < 4; ++mf)
        af[mf] = *reinterpret_cast<const short8*>(
            &Ac[(wm + mf * 16 + lr) * 64 + (((kb * 4 + g) ^ (lr & 7)) << 3)]);
#pragma unroll
      for (int mf = 0; mf < 4; ++mf)
#pragma unroll
        for (int nf = 0; nf < 4; ++nf)
          acc[mf][nf] = __builtin_amdgcn_mfma_f32_16x16x32_bf16(af[mf], bf[nf], acc[mf][nf], 0, 0, 0);
    }
    __syncthreads();
  }
#undef QKV_STAGE

  // ---- epilogue: C-tile -> LDS (stride 136) -> 16B coalesced global stores ----
  u16* Ct = smem;
  const int b = m0 >> 12;
  const int which = n0 >> 9;         // 0=Q, 1=K, 2=V
  const int nloc = m0 & 4095;

  if (which < 2) {
#pragma unroll
    for (int mf = 0; mf < 4; ++mf)
#pragma unroll
      for (int nf = 0; nf < 4; ++nf) {
        const int col_l = wn + nf * 16 + lr;
        float bv = bias[n0 + col_l];
        if (which == 0) bv *= SCQ;
#pragma unroll
        for (int r = 0; r < 4; ++r)
          Ct[(wm + mf * 16 + g * 4 + r) * 136 + col_l] = f2b(acc[mf][nf][r] + bv);
      }
    __syncthreads();
    u16* const dst0 = (which == 0) ? Qd : Kd;
#pragma unroll
    for (int p = 0; p < 8; ++p) {
      const int idx = p * 256 + tid;
      const int row = idx >> 4;
      const int c8 = (idx & 15) << 3;
      short8 v = *reinterpret_cast<const short8*>(&Ct[row * 136 + c8]);
      const int col = n0 + c8;
      const int h = (col & 511) >> 6, hd = col & 63;
      *reinterpret_cast<short8*>(
          dst0 + ((size_t)(b * 8 + h) * 4096 + nloc + row) * 64 + hd) = v;
    }
  } else {
#pragma unroll
    for (int mf = 0; mf < 4; ++mf)
#pragma unroll
      for (int nf = 0; nf < 4; ++nf) {
        const int col_l = wn + nf * 16 + lr;
        const float bv = bias[n0 + col_l];
        const int row0 = wm + mf * 16 + g * 4;
        ushort4 pk;
        pk.x = f2b(acc[mf][nf][0] + bv);
        pk.y = f2b(acc[mf][nf][1] + bv);
        pk.z = f2b(acc[mf][nf][2] + bv);
        pk.w = f2b(acc[mf][nf][3] + bv);
        *reinterpret_cast<ushort4*>(&Ct[col_l * 136 + row0]) = pk;
      }
    __syncthreads();
#pragma unroll
    for (int p = 0; p < 8; ++p) {
      const int idx = p * 256 + tid;
      const int col_l = idx >> 4;
      const int c8 = (idx & 15) << 3;
      short8 v = *reinterpret_cast<const short8*>(&Ct[col_l * 136 + c8]);
      const int col = n0 + col_l;
      const int h = (col & 511) >> 6, hd = col & 63;
      *reinterpret_cast<short8*>(
          Vtd + ((size_t)(b * 8 + h) * 64 + hd) * 4096 + nloc + c8) = v;
    }
  }
}

// ---------------- attention v20: qt=1, 3 waves/SIMD target --------------------------
// 32 q-rows/wave (128/block). Grid = 16 bh x 32 qb x 2 half = 1024 blocks.
// Same skeleton as r13 (T15 A/B half-pipeline, KVBLK=128 glds dbuf, slim softmax)
// with the qt dimension removed: per-wave footprint ~165 regs -> lb(256,3) gives
// 3 waves/SIMD WITHOUT the round-5/7 clamp-spill (qt=1 natural usage fits 170;
// r3's qt=1 fail was lb(256,4)'s 64-reg clamp + heavy per-iter staging).
// Pre-committed reads: WRITE >> 40 MB or VGPR <= 120 = spill -> revert r19;
// attn >= 90 us at clean counters = overhead ate occupancy -> structure final.
__global__ __launch_bounds__(256, 3) void attn20(
    const u16* __restrict__ Qd, const u16* __restrict__ Kd, const u16* __restrict__ Vtd,
    float* __restrict__ Op, float* __restrict__ Lp) {
  // XCD-aware remap: each XCD owns 2 bh (K/V L2-resident per XCD)
  int f = blockIdx.x;                 // 0..1023
  int xcd = f & 7, slot = f >> 3;     // slot 0..127
  int bh = (xcd << 1) + (slot >> 6);
  int rem = slot & 63;
  int half = rem >> 5;
  int qb = rem & 31;

  const int tid = threadIdx.x, wave = tid >> 6, lane = tid & 63;
  const int hi = lane >> 5, lq = lane & 31;

  const u16* Qh = Qd + (size_t)bh * (4096 * 64);
  const u16* Kh = Kd + (size_t)bh * (4096 * 64);
  const u16* Vh = Vtd + (size_t)bh * (64 * 4096);
  float* Oh = Op + (size_t)half * (8192 * 512);
  float* Lh = Lp + (size_t)half * (16 * 4096);

  __shared__ alignas(16) u16 Kl[2][128 * 64];  // double-buffered 128-row K tile (32 KB)

  const int qrow = qb * 128 + wave * 32;

  // Q fragments [s]: B-operand, col q = lane&31, k = 8*hi + j
  short8 qf[4];
#pragma unroll
  for (int s = 0; s < 4; ++s)
    qf[s] = *reinterpret_cast<const short8*>(
        Qh + (size_t)(qrow + lq) * 64 + s * 16 + hi * 8);

  f32x16 acc[2];  // [dt] O^T accumulators
#pragma unroll
  for (int dt = 0; dt < 2; ++dt)
#pragma unroll
    for (int i = 0; i < 16; ++i) acc[dt][i] = 0.0f;

  f32x16 Z;
#pragma unroll
  for (int i = 0; i < 16; ++i) Z[i] = 0.0f;

  float lrun = 0.0f;

  const int kv0 = half * 2048;
  const int gid0 = wave * 64 + lane;

  // prologue: stage 128-row tile 0 (pre-swizzled source, linear LDS dest)
#pragma unroll
  for (int c = 0; c < 4; ++c) {
    const int gid = c * 256 + gid0;
    const int row = gid >> 3;
    const int col = ((gid & 7) ^ (row & 7)) << 3;
    gl_lds16(Kh + (size_t)(kv0 + row) * 64 + col, &Kl[0][(c * 256 + wave * 64) * 8]);
  }
  __syncthreads();

  f32x16 stA, stB;
  short8 vfA[2][2], vfB[2][2];
  short8 pbA[2], pbB[2];

#define QK_HALF(st0, h)                                                             \
  {                                                                                 \
    const int rb = ((h) * 32 + lq) * 64;                                            \
    __builtin_amdgcn_s_setprio(1);                                                  \
    _Pragma("unroll")                                                               \
    for (int s = 0; s < 4; ++s) {                                                   \
      const int ch = ((2 * s + hi) ^ (lq & 7)) << 3;                                \
      short8 kf = *reinterpret_cast<const short8*>(&Kl[cur][rb + ch]);              \
      if (s == 0) st0 = __builtin_amdgcn_mfma_f32_32x32x16_bf16(kf, qf[0], Z, 0, 0, 0); \
      else        st0 = __builtin_amdgcn_mfma_f32_32x32x16_bf16(kf, qf[s], st0, 0, 0, 0); \
    }                                                                               \
    __builtin_amdgcn_s_setprio(0);                                                  \
  }

#define LOADV_HALF(vf, h)                                                           \
  {                                                                                 \
    const int off = kbase + (h) * 32 + hi * 8;                                      \
    vf[0][0] = *reinterpret_cast<const short8*>(Vh + (size_t)lq * 4096 + off);      \
    vf[0][1] = *reinterpret_cast<const short8*>(Vh + (size_t)(32 + lq) * 4096 + off); \
    vf[1][0] = *reinterpret_cast<const short8*>(Vh + (size_t)lq * 4096 + off + 16); \
    vf[1][1] = *reinterpret_cast<const short8*>(Vh + (size_t)(32 + lq) * 4096 + off + 16); \
  }

#define SM_HALF(stq, pbq)                                                           \
  {                                                                                 \
    f32x2 p2[8];                                                                    \
    _Pragma("unroll")                                                               \
    for (int j = 0; j < 8; ++j) {                                                   \
      p2[j][0] = ex2(stq[2 * j]);                                                   \
      p2[j][1] = ex2(stq[2 * j + 1]);                                               \
    }                                                                               \
    f32x2 s0 = (p2[0] + p2[1]) + (p2[2] + p2[3]);                                   \
    f32x2 s1 = (p2[4] + p2[5]) + (p2[6] + p2[7]);                                   \
    f32x2 sm = s0 + s1;                                                             \
    lrun += sm[0] + sm[1];                                                          \
    _Pragma("unroll")                                                               \
    for (int t = 0; t < 2; ++t) {                                                   \
      u32 wa = cvtpk(p2[4 * t + 0][0], p2[4 * t + 0][1]);                           \
      u32 wb = cvtpk(p2[4 * t + 2][0], p2[4 * t + 2][1]);                           \
      u32 wc = cvtpk(p2[4 * t + 1][0], p2[4 * t + 1][1]);                           \
      u32 wd = cvtpk(p2[4 * t + 3][0], p2[4 * t + 3][1]);                           \
      asm volatile("v_permlane32_swap_b32 %0, %1" : "+v"(wa), "+v"(wb));            \
      asm volatile("v_permlane32_swap_b32 %0, %1" : "+v"(wc), "+v"(wd));            \
      int4 wv;                                                                      \
      wv.x = (int)wa; wv.y = (int)wc; wv.z = (int)wb; wv.w = (int)wd;               \
      pbq[t] = __builtin_bit_cast(short8, wv);                                      \
    }                                                                               \
  }

#define PV_HALF(vf, pb)                                                             \
  {                                                                                 \
    __builtin_amdgcn_s_setprio(1);                                                  \
    _Pragma("unroll")                                                               \
    for (int t = 0; t < 2; ++t) {                                                   \
      acc[0] = __builtin_amdgcn_mfma_f32_32x32x16_bf16(vf[t][0], pb[t], acc[0], 0, 0, 0); \
      acc[1] = __builtin_amdgcn_mfma_f32_32x32x16_bf16(vf[t][1], pb[t], acc[1], 0, 0, 0); \
    }                                                                               \
    __builtin_amdgcn_s_setprio(0);                                                  \
  }

#pragma unroll 1
  for (int kt = 0; kt < 16; ++kt) {
    const int cur = kt & 1;
    const int kbase = kv0 + kt * 128;

    if (kt + 1 < 16) {
      const u16* kn = Kh + (size_t)(kbase + 128) * 64;
#pragma unroll
      for (int c = 0; c < 4; ++c) {
        const int gid = c * 256 + gid0;
        const int row = gid >> 3;
        const int col = ((gid & 7) ^ (row & 7)) << 3;
        gl_lds16(kn + (size_t)row * 64 + col, &Kl[cur ^ 1][(c * 256 + wave * 64) * 8]);
      }
    }

    // 4 halves of 32 KV rows, software-pipelined: QK(h+1) issues before SM(h)
    QK_HALF(stA, 0);
    LOADV_HALF(vfA, 0);
#pragma unroll
    for (int hp = 0; hp < 2; ++hp) {
      const int h = hp * 2;
      QK_HALF(stB, h + 1);
      LOADV_HALF(vfB, h + 1);
      SM_HALF(stA, pbA);
      PV_HALF(vfA, pbA);
      if (hp == 0) {
        QK_HALF(stA, h + 2);
        LOADV_HALF(vfA, h + 2);
      }
      SM_HALF(stB, pbB);
      PV_HALF(vfB, pbB);
    }

    __syncthreads();
  }
#undef QK_HALF
#undef LOADV_HALF
#undef SM_HALF
#undef PV_HALF

  // ---- epilogue: write partial O^T (f32) and partial l ----
  const int b = bh >> 3, h = bh & 7;
  {
    const int qn = qrow + lq;
    const size_t rowoff = ((size_t)(b * 4096 + qn)) * 512 + h * 64;
#pragma unroll
    for (int dt = 0; dt < 2; ++dt)
#pragma unroll
      for (int t = 0; t < 4; ++t) {
        f32x4 v4;
        v4[0] = acc[dt][4 * t + 0];
        v4[1] = acc[dt][4 * t + 1];
        v4[2] = acc[dt][4 * t + 2];
        v4[3] = acc[dt][4 * t + 3];
        *reinterpret_cast<f32x4*>(Oh + rowoff + dt * 32 + t * 8 + hi * 4) = v4;
      }
    float lt = lrun + __shfl_xor(lrun, 32);
    if (hi == 0) Lh[(bh << 12) + qn] = lt;
  }
}

// ---------------- combine: attn_bf16 = (O0+O1) / (l0+l1) --------------------------
__global__ __launch_bounds__(256) void combine_k(
    const float* __restrict__ Op, const float* __restrict__ Lp,
    u16* __restrict__ attnb) {
  int idx = blockIdx.x * 256 + threadIdx.x;  // float4 index, 1048576 total
  int row = idx >> 7, c4 = idx & 127;
  int b = row >> 12, n = row & 4095, h = c4 >> 4;
  int li = (((b << 3) + h) << 12) + n;
  float l = Lp[li] + Lp[li + 65536];
  float inv = 1.0f / l;
  const int STRIDE = 8192 * 512 / 4;  // float4 stride between partials
  float4 o0 = reinterpret_cast<const float4*>(Op)[idx];
  float4 o1 = reinterpret_cast<const float4*>(Op)[idx + STRIDE];
  ushort4 o;
  o.x = f2b((o0.x + o1.x) * inv);
  o.y = f2b((o0.y + o1.y) * inv);
  o.z = f2b((o0.z + o1.z) * inv);
  o.w = f2b((o0.w + o1.w) * inv);
  *reinterpret_cast<ushort4*>(attnb + (size_t)idx * 4) = o;
}

// ---------------- out projection v2: 128x128 tile, dbuf glds, fp32 out ------------
__global__ __launch_bounds__(256) void out_gemm(
    const u16* __restrict__ Ab, const u16* __restrict__ Bw, const float* __restrict__ bias,
    float* __restrict__ out) {
  const int m0 = blockIdx.x * 128, n0 = blockIdx.y * 128;
  const int tid = threadIdx.x, wave = tid >> 6, lane = tid & 63;
  const int g = lane >> 4, lr = lane & 15;
  const int wm = (wave >> 1) * 64, wn = (wave & 1) * 64;
  __shared__ alignas(16) u16 smem[32768];

  f32x4 acc[4][4];
#pragma unroll
  for (int mf = 0; mf < 4; ++mf)
#pragma unroll
    for (int nf = 0; nf < 4; ++nf)
#pragma unroll
      for (int r = 0; r < 4; ++r) acc[mf][nf][r] = 0.0f;

  const int gid0 = wave * 64 + lane;

#define OUT_STAGE(buf, k0)                                                         \
  {                                                                                \
    u16* Ad_ = smem + (buf) * 8192;                                                \
    u16* Bd_ = smem + 16384 + (buf) * 8192;                                        \
    _Pragma("unroll")                                                              \
    for (int c = 0; c < 4; ++c) {                                                  \
      const int gid = c * 256 + gid0;                                              \
      const int row = gid >> 3;                                                    \
      const int col = ((gid & 7) ^ (row & 7)) << 3;                                \
      gl_lds16(Ab + (size_t)(m0 + row) * 512 + (k0) + col,                         \
               Ad_ + (size_t)(c * 256 + wave * 64) * 8);                           \
      gl_lds16(Bw + (size_t)(n0 + row) * 512 + (k0) + col,                         \
               Bd_ + (size_t)(c * 256 + wave * 64) * 8);                           \
    }                                                                              \
  }

  OUT_STAGE(0, 0);
  __syncthreads();

#pragma unroll 1
  for (int kt = 0; kt < 8; ++kt) {
    const int cur = kt & 1;
    if (kt + 1 < 8) OUT_STAGE(cur ^ 1, (kt + 1) * 64);

    const u16* Ac = smem + cur * 8192;
    const u16* Bc = smem + 16384 + cur * 8192;
#pragma unroll
    for (int kb = 0; kb < 2; ++kb) {
      short8 bf[4], af[4];
#pragma unroll
      for (int nf = 0; nf < 4; ++nf)
        bf[nf] = *reinterpret_cast<const short8*>(
            &Bc[(wn + nf * 16 + lr) * 64 + (((kb * 4 + g) ^ (lr & 7)) << 3)]);
#pragma unroll
      for (int mf = 0; mf < 4; ++mf)
        af[mf] = *reinterpret_cast<const short8*>(
            &Ac[(wm + mf * 16 + lr) * 64 + (((kb * 4 + g) ^ (lr & 7)) << 3)]);
#pragma unroll
      for (int mf = 0; mf < 4; ++mf)
#pragma unroll
        for (int nf = 0; nf < 4; ++nf)
          acc[mf][nf] = __builtin_amdgcn_mfma_f32_16x16x32_bf16(af[mf], bf[nf], acc[mf][nf], 0, 0, 0);
    }
    __syncthreads();
  }
#undef OUT_STAGE

#pragma unroll
  for (int mf = 0; mf < 4; ++mf)
#pragma unroll
    for (int nf = 0; nf < 4; ++nf)
#pragma unroll
      for (int r = 0; r < 4; ++r) {
        int row = m0 + wm + mf * 16 + g * 4 + r;
        int col = n0 + wn + nf * 16 + lr;
        out[(size_t)row * 512 + col] = acc[mf][nf][r] + bias[col];
      }
}

extern "C" void kernel_launch(void* const* d_in, const int* in_sizes, int n_in,
                              void* d_out, int out_size, void* d_ws, size_t ws_size,
                              hipStream_t stream) {
  const float* x = (const float*)d_in[0];
  const float* qkv_w = (const float*)d_in[1];
  const float* qkv_b = (const float*)d_in[2];
  const float* out_w = (const float*)d_in[3];
  const float* out_b = (const float*)d_in[4];
  float* out = (float*)d_out;

  char* ws = (char*)d_ws;
  u16* xb    = (u16*)(ws + 0);          //  8 MB  [8192][512]
  u16* w1b   = (u16*)(ws + 8388608);    //  1.5MB [1536][512]
  u16* w2b   = (u16*)(ws + 9961472);    //  0.5MB [512][512]
  u16* Qd    = (u16*)(ws + 10485760);   //  8 MB  [2,8,4096,64]
  u16* Kd    = (u16*)(ws + 18874368);   //  8 MB
  u16* Vtd   = (u16*)(ws + 27262976);   //  8 MB  [2,8,64,4096]
  u16* attnb = (u16*)(ws + 35651584);   //  8 MB  [8192][512]
  float* Op  = (float*)(ws + 44040192); // 32 MB  [2][8192][512] partial O
  float* Lp  = (float*)(ws + 77594624); // 512 KB [2][16][4096]  partial l

  convert_k<<<5120, 256, 0, stream>>>(x, qkv_w, out_w, xb, w1b, w2b);
  qkv_gemm<<<dim3(64, 12), 256, 0, stream>>>(xb, w1b, qkv_b, Qd, Kd, Vtd);
  attn20<<<1024, 256, 0, stream>>>(Qd, Kd, Vtd, Op, Lp);
  combine_k<<<4096, 256, 0, stream>>>(Op, Lp, attnb);
  out_gemm<<<dim3(64, 4), 256, 0, stream>>>(attnb, w2b, out_b, out);
}

// Round 21
// 131.235 us; speedup vs baseline: 1.3840x; 1.3840x over previous
//
#include <hip/hip_runtime.h>

typedef __attribute__((ext_vector_type(8))) short short8;
typedef __attribute__((ext_vector_type(2))) float f32x2;
typedef __attribute__((ext_vector_type(4))) float f32x4;
typedef __attribute__((ext_vector_type(16))) float f32x16;
typedef unsigned short u16;
typedef unsigned int u32;

// 0.125 (1/sqrt(64)) * log2(e): folded into q so softmax can use exp2 directly
#define SCQ 0.18033688011112042f

__device__ __forceinline__ u16 f2b(float f) {
  unsigned u = __builtin_bit_cast(unsigned, f);
  u += 0x7FFFu + ((u >> 16) & 1u);
  return (u16)(u >> 16);
}

__device__ __forceinline__ u32 cvtpk(float a, float b) {
  u32 r;
  asm("v_cvt_pk_bf16_f32 %0, %1, %2" : "=v"(r) : "v"(a), "v"(b));
  return r;
}

// bare v_exp_f32 (scores |s| <~ 10, libm range-fixup provably dead; r10: -35us VALU)
__device__ __forceinline__ float ex2(float x) { return __builtin_amdgcn_exp2f(x); }

// async global->LDS, 16B per lane; LDS dest = wave-uniform base + lane*16
__device__ __forceinline__ void gl_lds16(const u16* g, u16* l) {
  __builtin_amdgcn_global_load_lds(
      (const __attribute__((address_space(1))) unsigned int*)g,
      (__attribute__((address_space(3))) unsigned int*)l, 16, 0, 0);
}

// ---------------- fp32 -> bf16 conversion (x, qkv_w [q-rows pre-scaled], out_w) ---
__global__ __launch_bounds__(256) void convert_k(
    const float* __restrict__ x, const float* __restrict__ w1, const float* __restrict__ w2,
    u16* __restrict__ xb, u16* __restrict__ w1b, u16* __restrict__ w2b) {
  const int NXv = (8192 * 512) / 4;
  const int NW1v = (1536 * 512) / 4;
  const int NW2v = (512 * 512) / 4;
  int i = blockIdx.x * 256 + threadIdx.x;
  const float4* src;
  u16* dst;
  int j;
  float scale = 1.0f;
  if (i < NXv) {
    src = (const float4*)x; dst = xb; j = i;
  } else if (i < NXv + NW1v) {
    j = i - NXv; src = (const float4*)w1; dst = w1b;
    if (j < (512 * 512) / 4) scale = SCQ;  // q-weight rows
  } else {
    j = i - NXv - NW1v;
    if (j >= NW2v) return;
    src = (const float4*)w2; dst = w2b;
  }
  float4 v = src[j];
  ushort4 o;
  o.x = f2b(v.x * scale); o.y = f2b(v.y * scale);
  o.z = f2b(v.z * scale); o.w = f2b(v.w * scale);
  *reinterpret_cast<ushort4*>(dst + (size_t)j * 4) = o;
}

// ---------------- QKV GEMM v4: double-buffered glds + LDS-transposed epilogue -----
__global__ __launch_bounds__(256) void qkv_gemm(
    const u16* __restrict__ Ab, const u16* __restrict__ Bw, const float* __restrict__ bias,
    u16* __restrict__ Qd, u16* __restrict__ Kd, u16* __restrict__ Vtd) {
  const int m0 = blockIdx.x * 128, n0 = blockIdx.y * 128;
  const int tid = threadIdx.x, wave = tid >> 6, lane = tid & 63;
  const int g = lane >> 4, lr = lane & 15;
  const int wm = (wave >> 1) * 64, wn = (wave & 1) * 64;
  __shared__ alignas(16) u16 smem[32768];  // 64KB: A dbuf @0/8192, B dbuf @16384/24576

  f32x4 acc[4][4];
#pragma unroll
  for (int mf = 0; mf < 4; ++mf)
#pragma unroll
    for (int nf = 0; nf < 4; ++nf)
#pragma unroll
      for (int r = 0; r < 4; ++r) acc[mf][nf][r] = 0.0f;

  const int gid0 = wave * 64 + lane;

#define QKV_STAGE(buf, k0)                                                         \
  {                                                                                \
    u16* Ad_ = smem + (buf) * 8192;                                                \
    u16* Bd_ = smem + 16384 + (buf) * 8192;                                        \
    _Pragma("unroll")                                                              \
    for (int c = 0; c < 4; ++c) {                                                  \
      const int gid = c * 256 + gid0;                                              \
      const int row = gid >> 3;                                                    \
      const int col = ((gid & 7) ^ (row & 7)) << 3;                                \
      gl_lds16(Ab + (size_t)(m0 + row) * 512 + (k0) + col,                         \
               Ad_ + (size_t)(c * 256 + wave * 64) * 8);                           \
      gl_lds16(Bw + (size_t)(n0 + row) * 512 + (k0) + col,                         \
               Bd_ + (size_t)(c * 256 + wave * 64) * 8);                           \
    }                                                                              \
  }

  QKV_STAGE(0, 0);
  __syncthreads();

#pragma unroll 1
  for (int kt = 0; kt < 8; ++kt) {
    const int cur = kt & 1;
    if (kt + 1 < 8) QKV_STAGE(cur ^ 1, (kt + 1) * 64);

    const u16* Ac = smem + cur * 8192;
    const u16* Bc = smem + 16384 + cur * 8192;
#pragma unroll
    for (int kb = 0; kb < 2; ++kb) {
      short8 bf[4], af[4];
#pragma unroll
      for (int nf = 0; nf < 4; ++nf)
        bf[nf] = *reinterpret_cast<const short8*>(
            &Bc[(wn + nf * 16 + lr) * 64 + (((kb * 4 + g) ^ (lr & 7)) << 3)]);
#pragma unroll
      for (int mf = 0; mf < 4; ++mf)
        af[mf] = *reinterpret_cast<const short8*>(
            &Ac[(wm + mf * 16 + lr) * 64 + (((kb * 4 + g) ^ (lr & 7)) << 3)]);
#pragma unroll
      for (int mf = 0; mf < 4; ++mf)
#pragma unroll
        for (int nf = 0; nf < 4; ++nf)
          acc[mf][nf] = __builtin_amdgcn_mfma_f32_16x16x32_bf16(af[mf], bf[nf], acc[mf][nf], 0, 0, 0);
    }
    __syncthreads();
  }
#undef QKV_STAGE

  // ---- epilogue: C-tile -> LDS (stride 136) -> 16B coalesced global stores ----
  u16* Ct = smem;
  const int b = m0 >> 12;
  const int which = n0 >> 9;         // 0=Q, 1=K, 2=V
  const int nloc = m0 & 4095;

  if (which < 2) {
#pragma unroll
    for (int mf = 0; mf < 4; ++mf)
#pragma unroll
      for (int nf = 0; nf < 4; ++nf) {
        const int col_l = wn + nf * 16 + lr;
        float bv = bias[n0 + col_l];
        if (which == 0) bv *= SCQ;
#pragma unroll
        for (int r = 0; r < 4; ++r)
          Ct[(wm + mf * 16 + g * 4 + r) * 136 + col_l] = f2b(acc[mf][nf][r] + bv);
      }
    __syncthreads();
    u16* const dst0 = (which == 0) ? Qd : Kd;
#pragma unroll
    for (int p = 0; p < 8; ++p) {
      const int idx = p * 256 + tid;
      const int row = idx >> 4;
      const int c8 = (idx & 15) << 3;
      short8 v = *reinterpret_cast<const short8*>(&Ct[row * 136 + c8]);
      const int col = n0 + c8;
      const int h = (col & 511) >> 6, hd = col & 63;
      *reinterpret_cast<short8*>(
          dst0 + ((size_t)(b * 8 + h) * 4096 + nloc + row) * 64 + hd) = v;
    }
  } else {
#pragma unroll
    for (int mf = 0; mf < 4; ++mf)
#pragma unroll
      for (int nf = 0; nf < 4; ++nf) {
        const int col_l = wn + nf * 16 + lr;
        const float bv = bias[n0 + col_l];
        const int row0 = wm + mf * 16 + g * 4;
        ushort4 pk;
        pk.x = f2b(acc[mf][nf][0] + bv);
        pk.y = f2b(acc[mf][nf][1] + bv);
        pk.z = f2b(acc[mf][nf][2] + bv);
        pk.w = f2b(acc[mf][nf][3] + bv);
        *reinterpret_cast<ushort4*>(&Ct[col_l * 136 + row0]) = pk;
      }
    __syncthreads();
#pragma unroll
    for (int p = 0; p < 8; ++p) {
      const int idx = p * 256 + tid;
      const int col_l = idx >> 4;
      const int c8 = (idx & 15) << 3;
      short8 v = *reinterpret_cast<const short8*>(&Ct[col_l * 136 + c8]);
      const int col = n0 + col_l;
      const int h = (col & 511) >> 6, hd = col & 63;
      *reinterpret_cast<short8*>(
          Vtd + ((size_t)(b * 8 + h) * 64 + hd) * 4096 + nloc + c8) = v;
    }
  }
}

// ---------------- attention v13 (best: 92.6 us): T15 half-pipeline ----------------
// qt=2 structure FINAL: qt=1 at 3 waves/SIMD (r20) regressed 93->147 despite
// +50% occupancy (work/overhead ratio loss; r3 lesson re-confirmed). Ceiling
// decomposition: MFMA-busy 28us (== 27.5us bf16 dense-peak floor), VALU-busy
// 32us (exp2 trans floor ~14), stall ~33us hidden only by more waves -- blocked
// by the ~250-reg/wave footprint of the 64q x 64KV working set.
__global__ __launch_bounds__(256, 2) void attn13(
    const u16* __restrict__ Qd, const u16* __restrict__ Kd, const u16* __restrict__ Vtd,
    float* __restrict__ Op, float* __restrict__ Lp) {
  // XCD-aware remap: each XCD owns 2 bh (K/V L2-resident per XCD)
  int f = blockIdx.x;                 // 0..511
  int xcd = f & 7, slot = f >> 3;     // slot 0..63
  int bh = (xcd << 1) + (slot >> 5);
  int rem = slot & 31;
  int half = rem >> 4;
  int qb = rem & 15;

  const int tid = threadIdx.x, wave = tid >> 6, lane = tid & 63;
  const int hi = lane >> 5, lq = lane & 31;

  const u16* Qh = Qd + (size_t)bh * (4096 * 64);
  const u16* Kh = Kd + (size_t)bh * (4096 * 64);
  const u16* Vh = Vtd + (size_t)bh * (64 * 4096);
  float* Oh = Op + (size_t)half * (8192 * 512);
  float* Lh = Lp + (size_t)half * (16 * 4096);

  __shared__ alignas(16) u16 Kl[2][128 * 64];  // double-buffered 128-row K tile (32 KB)

  const int qrow_base = qb * 256 + wave * 64;

  short8 qf[2][4];
#pragma unroll
  for (int qt = 0; qt < 2; ++qt)
#pragma unroll
    for (int s = 0; s < 4; ++s)
      qf[qt][s] = *reinterpret_cast<const short8*>(
          Qh + (size_t)(qrow_base + qt * 32 + lq) * 64 + s * 16 + hi * 8);

  f32x16 acc[2][2];
#pragma unroll
  for (int qt = 0; qt < 2; ++qt)
#pragma unroll
    for (int dt = 0; dt < 2; ++dt)
#pragma unroll
      for (int i = 0; i < 16; ++i) acc[qt][dt][i] = 0.0f;

  f32x16 Z;
#pragma unroll
  for (int i = 0; i < 16; ++i) Z[i] = 0.0f;

  float lrun[2] = {0.0f, 0.0f};

  const int kv0 = half * 2048;
  const int gid0 = wave * 64 + lane;

  // prologue: stage 128-row tile 0 (pre-swizzled source, linear LDS dest)
#pragma unroll
  for (int c = 0; c < 4; ++c) {
    const int gid = c * 256 + gid0;
    const int row = gid >> 3;
    const int col = ((gid & 7) ^ (row & 7)) << 3;
    gl_lds16(Kh + (size_t)(kv0 + row) * 64 + col, &Kl[0][(c * 256 + wave * 64) * 8]);
  }
  __syncthreads();

  f32x16 stA0, stA1, stB0, stB1;
  short8 vfA[2][2], vfB[2][2];
  short8 pbA0[2], pbA1[2], pbB0[2], pbB1[2];

#define QK_HALF(st0, st1, h)                                                        \
  {                                                                                 \
    const int rb = ((h) * 32 + lq) * 64;                                            \
    __builtin_amdgcn_s_setprio(1);                                                  \
    _Pragma("unroll")                                                               \
    for (int s = 0; s < 4; ++s) {                                                   \
      const int ch = ((2 * s + hi) ^ (lq & 7)) << 3;                                \
      short8 kf = *reinterpret_cast<const short8*>(&Kl[cur][rb + ch]);              \
      if (s == 0) {                                                                 \
        st0 = __builtin_amdgcn_mfma_f32_32x32x16_bf16(kf, qf[0][0], Z, 0, 0, 0);    \
        st1 = __builtin_amdgcn_mfma_f32_32x32x16_bf16(kf, qf[1][0], Z, 0, 0, 0);    \
      } else {                                                                      \
        st0 = __builtin_amdgcn_mfma_f32_32x32x16_bf16(kf, qf[0][s], st0, 0, 0, 0);  \
        st1 = __builtin_amdgcn_mfma_f32_32x32x16_bf16(kf, qf[1][s], st1, 0, 0, 0);  \
      }                                                                             \
    }                                                                               \
    __builtin_amdgcn_s_setprio(0);                                                  \
  }

#define LOADV_HALF(vf, h)                                                           \
  {                                                                                 \
    const int off = kbase + (h) * 32 + hi * 8;                                      \
    vf[0][0] = *reinterpret_cast<const short8*>(Vh + (size_t)lq * 4096 + off);      \
    vf[0][1] = *reinterpret_cast<const short8*>(Vh + (size_t)(32 + lq) * 4096 + off); \
    vf[1][0] = *reinterpret_cast<const short8*>(Vh + (size_t)lq * 4096 + off + 16); \
    vf[1][1] = *reinterpret_cast<const short8*>(Vh + (size_t)(32 + lq) * 4096 + off + 16); \
  }

#define SM_QT(stq, pbq, qt_idx)                                                     \
  {                                                                                 \
    f32x2 p2[8];                                                                    \
    _Pragma("unroll")                                                               \
    for (int j = 0; j < 8; ++j) {                                                   \
      p2[j][0] = ex2(stq[2 * j]);                                                   \
      p2[j][1] = ex2(stq[2 * j + 1]);                                               \
    }                                                                               \
    f32x2 s0 = (p2[0] + p2[1]) + (p2[2] + p2[3]);                                   \
    f32x2 s1 = (p2[4] + p2[5]) + (p2[6] + p2[7]);                                   \
    f32x2 sm = s0 + s1;                                                             \
    lrun[qt_idx] += sm[0] + sm[1];                                                  \
    _Pragma("unroll")                                                               \
    for (int t = 0; t < 2; ++t) {                                                   \
      u32 wa = cvtpk(p2[4 * t + 0][0], p2[4 * t + 0][1]);                           \
      u32 wb = cvtpk(p2[4 * t + 2][0], p2[4 * t + 2][1]);                           \
      u32 wc = cvtpk(p2[4 * t + 1][0], p2[4 * t + 1][1]);                           \
      u32 wd = cvtpk(p2[4 * t + 3][0], p2[4 * t + 3][1]);                           \
      asm volatile("v_permlane32_swap_b32 %0, %1" : "+v"(wa), "+v"(wb));            \
      asm volatile("v_permlane32_swap_b32 %0, %1" : "+v"(wc), "+v"(wd));            \
      int4 wv;                                                                      \
      wv.x = (int)wa; wv.y = (int)wc; wv.z = (int)wb; wv.w = (int)wd;               \
      pbq[t] = __builtin_bit_cast(short8, wv);                                      \
    }                                                                               \
  }

#define PV_HALF(vf, pb0, pb1)                                                       \
  {                                                                                 \
    __builtin_amdgcn_s_setprio(1);                                                  \
    _Pragma("unroll")                                                               \
    for (int t = 0; t < 2; ++t) {                                                   \
      acc[0][0] = __builtin_amdgcn_mfma_f32_32x32x16_bf16(vf[t][0], pb0[t], acc[0][0], 0, 0, 0); \
      acc[0][1] = __builtin_amdgcn_mfma_f32_32x32x16_bf16(vf[t][1], pb0[t], acc[0][1], 0, 0, 0); \
      acc[1][0] = __builtin_amdgcn_mfma_f32_32x32x16_bf16(vf[t][0], pb1[t], acc[1][0], 0, 0, 0); \
      acc[1][1] = __builtin_amdgcn_mfma_f32_32x32x16_bf16(vf[t][1], pb1[t], acc[1][1], 0, 0, 0); \
    }                                                                               \
    __builtin_amdgcn_s_setprio(0);                                                  \
  }

#pragma unroll 1
  for (int kt = 0; kt < 16; ++kt) {
    const int cur = kt & 1;
    const int kbase = kv0 + kt * 128;

    if (kt + 1 < 16) {
      const u16* kn = Kh + (size_t)(kbase + 128) * 64;
#pragma unroll
      for (int c = 0; c < 4; ++c) {
        const int gid = c * 256 + gid0;
        const int row = gid >> 3;
        const int col = ((gid & 7) ^ (row & 7)) << 3;
        gl_lds16(kn + (size_t)row * 64 + col, &Kl[cur ^ 1][(c * 256 + wave * 64) * 8]);
      }
    }

    // 4 halves of 32 KV rows, software-pipelined: QK(h+1) issues before SM(h)
    QK_HALF(stA0, stA1, 0);
    LOADV_HALF(vfA, 0);
#pragma unroll
    for (int hp = 0; hp < 2; ++hp) {
      const int h = hp * 2;
      QK_HALF(stB0, stB1, h + 1);
      LOADV_HALF(vfB, h + 1);
      SM_QT(stA0, pbA0, 0);
      SM_QT(stA1, pbA1, 1);
      PV_HALF(vfA, pbA0, pbA1);
      if (hp == 0) {
        QK_HALF(stA0, stA1, h + 2);
        LOADV_HALF(vfA, h + 2);
      }
      SM_QT(stB0, pbB0, 0);
      SM_QT(stB1, pbB1, 1);
      PV_HALF(vfB, pbB0, pbB1);
    }

    __syncthreads();
  }
#undef QK_HALF
#undef LOADV_HALF
#undef SM_QT
#undef PV_HALF

  const int b = bh >> 3, h = bh & 7;
#pragma unroll
  for (int qt = 0; qt < 2; ++qt) {
    const int qn = qrow_base + qt * 32 + lq;
    const size_t rowoff = ((size_t)(b * 4096 + qn)) * 512 + h * 64;
#pragma unroll
    for (int dt = 0; dt < 2; ++dt)
#pragma unroll
      for (int t = 0; t < 4; ++t) {
        f32x4 v4;
        v4[0] = acc[qt][dt][4 * t + 0];
        v4[1] = acc[qt][dt][4 * t + 1];
        v4[2] = acc[qt][dt][4 * t + 2];
        v4[3] = acc[qt][dt][4 * t + 3];
        *reinterpret_cast<f32x4*>(Oh + rowoff + dt * 32 + t * 8 + hi * 4) = v4;
      }
    float lt = lrun[qt] + __shfl_xor(lrun[qt], 32);
    if (hi == 0) Lh[(bh << 12) + qn] = lt;
  }
}

// ---------------- combine: attn_bf16 = (O0+O1) / (l0+l1) --------------------------
__global__ __launch_bounds__(256) void combine_k(
    const float* __restrict__ Op, const float* __restrict__ Lp,
    u16* __restrict__ attnb) {
  int idx = blockIdx.x * 256 + threadIdx.x;  // float4 index, 1048576 total
  int row = idx >> 7, c4 = idx & 127;
  int b = row >> 12, n = row & 4095, h = c4 >> 4;
  int li = (((b << 3) + h) << 12) + n;
  float l = Lp[li] + Lp[li + 65536];
  float inv = 1.0f / l;
  const int STRIDE = 8192 * 512 / 4;  // float4 stride between partials
  float4 o0 = reinterpret_cast<const float4*>(Op)[idx];
  float4 o1 = reinterpret_cast<const float4*>(Op)[idx + STRIDE];
  ushort4 o;
  o.x = f2b((o0.x + o1.x) * inv);
  o.y = f2b((o0.y + o1.y) * inv);
  o.z = f2b((o0.z + o1.z) * inv);
  o.w = f2b((o0.w + o1.w) * inv);
  *reinterpret_cast<ushort4*>(attnb + (size_t)idx * 4) = o;
}

// ---------------- out projection v2: 128x128 tile, dbuf glds, fp32 out ------------
__global__ __launch_bounds__(256) void out_gemm(
    const u16* __restrict__ Ab, const u16* __restrict__ Bw, const float* __restrict__ bias,
    float* __restrict__ out) {
  const int m0 = blockIdx.x * 128, n0 = blockIdx.y * 128;
  const int tid = threadIdx.x, wave = tid >> 6, lane = tid & 63;
  const int g = lane >> 4, lr = lane & 15;
  const int wm = (wave >> 1) * 64, wn = (wave & 1) * 64;
  __shared__ alignas(16) u16 smem[32768];

  f32x4 acc[4][4];
#pragma unroll
  for (int mf = 0; mf < 4; ++mf)
#pragma unroll
    for (int nf = 0; nf < 4; ++nf)
#pragma unroll
      for (int r = 0; r < 4; ++r) acc[mf][nf][r] = 0.0f;

  const int gid0 = wave * 64 + lane;

#define OUT_STAGE(buf, k0)                                                         \
  {                                                                                \
    u16* Ad_ = smem + (buf) * 8192;                                                \
    u16* Bd_ = smem + 16384 + (buf) * 8192;                                        \
    _Pragma("unroll")                                                              \
    for (int c = 0; c < 4; ++c) {                                                  \
      const int gid = c * 256 + gid0;                                              \
      const int row = gid >> 3;                                                    \
      const int col = ((gid & 7) ^ (row & 7)) << 3;                                \
      gl_lds16(Ab + (size_t)(m0 + row) * 512 + (k0) + col,                         \
               Ad_ + (size_t)(c * 256 + wave * 64) * 8);                           \
      gl_lds16(Bw + (size_t)(n0 + row) * 512 + (k0) + col,                         \
               Bd_ + (size_t)(c * 256 + wave * 64) * 8);                           \
    }                                                                              \
  }

  OUT_STAGE(0, 0);
  __syncthreads();

#pragma unroll 1
  for (int kt = 0; kt < 8; ++kt) {
    const int cur = kt & 1;
    if (kt + 1 < 8) OUT_STAGE(cur ^ 1, (kt + 1) * 64);

    const u16* Ac = smem + cur * 8192;
    const u16* Bc = smem + 16384 + cur * 8192;
#pragma unroll
    for (int kb = 0; kb < 2; ++kb) {
      short8 bf[4], af[4];
#pragma unroll
      for (int nf = 0; nf < 4; ++nf)
        bf[nf] = *reinterpret_cast<const short8*>(
            &Bc[(wn + nf * 16 + lr) * 64 + (((kb * 4 + g) ^ (lr & 7)) << 3)]);
#pragma unroll
      for (int mf = 0; mf < 4; ++mf)
        af[mf] = *reinterpret_cast<const short8*>(
            &Ac[(wm + mf * 16 + lr) * 64 + (((kb * 4 + g) ^ (lr & 7)) << 3)]);
#pragma unroll
      for (int mf = 0; mf < 4; ++mf)
#pragma unroll
        for (int nf = 0; nf < 4; ++nf)
          acc[mf][nf] = __builtin_amdgcn_mfma_f32_16x16x32_bf16(af[mf], bf[nf], acc[mf][nf], 0, 0, 0);
    }
    __syncthreads();
  }
#undef OUT_STAGE

#pragma unroll
  for (int mf = 0; mf < 4; ++mf)
#pragma unroll
    for (int nf = 0; nf < 4; ++nf)
#pragma unroll
      for (int r = 0; r < 4; ++r) {
        int row = m0 + wm + mf * 16 + g * 4 + r;
        int col = n0 + wn + nf * 16 + lr;
        out[(size_t)row * 512 + col] = acc[mf][nf][r] + bias[col];
      }
}

extern "C" void kernel_launch(void* const* d_in, const int* in_sizes, int n_in,
                              void* d_out, int out_size, void* d_ws, size_t ws_size,
                              hipStream_t stream) {
  const float* x = (const float*)d_in[0];
  const float* qkv_w = (const float*)d_in[1];
  const float* qkv_b = (const float*)d_in[2];
  const float* out_w = (const float*)d_in[3];
  const float* out_b = (const float*)d_in[4];
  float* out = (float*)d_out;

  char* ws = (char*)d_ws;
  u16* xb    = (u16*)(ws + 0);          //  8 MB  [8192][512]
  u16* w1b   = (u16*)(ws + 8388608);    //  1.5MB [1536][512]
  u16* w2b   = (u16*)(ws + 9961472);    //  0.5MB [512][512]
  u16* Qd    = (u16*)(ws + 10485760);   //  8 MB  [2,8,4096,64]
  u16* Kd    = (u16*)(ws + 18874368);   //  8 MB
  u16* Vtd   = (u16*)(ws + 27262976);   //  8 MB  [2,8,64,4096]
  u16* attnb = (u16*)(ws + 35651584);   //  8 MB  [8192][512]
  float* Op  = (float*)(ws + 44040192); // 32 MB  [2][8192][512] partial O
  float* Lp  = (float*)(ws + 77594624); // 512 KB [2][16][4096]  partial l

  convert_k<<<5120, 256, 0, stream>>>(x, qkv_w, out_w, xb, w1b, w2b);
  qkv_gemm<<<dim3(64, 12), 256, 0, stream>>>(xb, w1b, qkv_b, Qd, Kd, Vtd);
  attn13<<<512, 256, 0, stream>>>(Qd, Kd, Vtd, Op, Lp);
  combine_k<<<4096, 256, 0, stream>>>(Op, Lp, attnb);
  out_gemm<<<dim3(64, 4), 256, 0, stream>>>(attnb, w2b, out_b, out);
}